// Round 1
// baseline (44800.897 us; speedup 1.0000x reference)
//
#include <hip/hip_runtime.h>
#include <cstdint>
#include <cstddef>

// LowRankRNN: h_{t+1} = h + coef*(-h + J@relu(h) + I_t),  J = G*W - B/N + M u v^T
//
// Persistent kernel, 64 blocks x 512 threads (1 block/CU), J in registers
// (128 f32/lane). SYNC REDESIGN vs previous version: no flags, no barriers.
// Since x = relu(h) >= 0, the SIGN BIT of each stored x value is a sequencing
// token: x(t) is stored sign-encoded by phase enc(t)=(t>>1)&1 (phase 1 => sign
// set; exact, pure sign-bit flip; decoded by negating the REDUCED dot product,
// which commutes exactly with FP add/mul). Two buffers alternate by t&1, so
// consecutive occupants of a buffer have opposite phase -> stale values can
// never satisfy the poll. Consumers poll the data directly with
// global_load_dwordx4 sc0 sc1 (LLC-coherent, no buffer_inv/wbl2, no flag round
// trip, data arrives WITH the poll). Waves are fully independent: zero
// __syncthreads in the main loop.
//
// Overwrite safety: a block stores x(t+2) only after its poll of x(t+1)
// succeeded, i.e. after ALL blocks stored x(t+1), i.e. after all blocks
// finished reading buffer t&1. So no producer can clobber a buffer a slow
// block still needs. Per-slot 32-bit store atomicity is the only ordering
// requirement; mixed stale/fresh values within a chunk are caught per-value
// by the sign check.

constexpr int   NN   = 2048;
constexpr int   TT   = 8192;
constexpr float COEF = 0.001f;             // DT/TAU
constexpr float G_   = 2.0f;
constexpr float BOFF = 10.0f / 2048.0f;    // B/N
constexpr float M_   = 1.5f;

constexpr int NBLK = 64;    // 1 block/CU
constexpr int TPB  = 512;   // 8 waves
constexpr int WPB  = TPB / 64;

typedef float f32x4 __attribute__((ext_vector_type(4)));
typedef int   i32x4 __attribute__((ext_vector_type(4)));

__device__ __forceinline__ i32x4 bc(const f32x4 x) {
  return __builtin_bit_cast(i32x4, x);
}

// buf0 polled first at t=2 expecting sign-SET  -> init sign-clear (waits)
// buf1 polled first at t=1 expecting sign-CLEAR -> init sign-set  (waits)
__global__ void init_xbufs(float* xb) {
  const int i = blockIdx.x * blockDim.x + threadIdx.x;   // 0..NN-1
  __hip_atomic_store(xb + i,      0.0f,  __ATOMIC_RELAXED, __HIP_MEMORY_SCOPE_AGENT);
  __hip_atomic_store(xb + NN + i, -1.0f, __ATOMIC_RELAXED, __HIP_MEMORY_SCOPE_AGENT);
}

// 8x dwordx4 LLC-coherent loads + waitcnt in ONE asm block (waitcnt inside the
// producing asm => consumers are ordered by register dataflow; rule-#18 safe).
// Base is biased +4096B so all 8 chunks fit the 13-bit signed imm offset.
__device__ __forceinline__ void poll8(const float* pb, f32x4 c[8]) {
  asm volatile(
      "global_load_dwordx4 %0, %8, off offset:-4096 sc0 sc1\n\t"
      "global_load_dwordx4 %1, %8, off offset:-3072 sc0 sc1\n\t"
      "global_load_dwordx4 %2, %8, off offset:-2048 sc0 sc1\n\t"
      "global_load_dwordx4 %3, %8, off offset:-1024 sc0 sc1\n\t"
      "global_load_dwordx4 %4, %8, off sc0 sc1\n\t"
      "global_load_dwordx4 %5, %8, off offset:1024 sc0 sc1\n\t"
      "global_load_dwordx4 %6, %8, off offset:2048 sc0 sc1\n\t"
      "global_load_dwordx4 %7, %8, off offset:3072 sc0 sc1\n\t"
      "s_waitcnt vmcnt(0)"
      : "=&v"(c[0]), "=&v"(c[1]), "=&v"(c[2]), "=&v"(c[3]),
        "=&v"(c[4]), "=&v"(c[5]), "=&v"(c[6]), "=&v"(c[7])
      : "v"(pb)
      : "memory");
}

__global__ __launch_bounds__(TPB, 2)
void rnn_persist(const float* __restrict__ I_t,
                 const float* __restrict__ h0,
                 const float* __restrict__ W,
                 const float* __restrict__ u,
                 const float* __restrict__ v,
                 float* __restrict__ out_h,   // d_out + TT, [TT][NN]
                 float* __restrict__ xbuf)    // 2*NN floats
{
  const int tid = threadIdx.x;
  const int l   = tid & 63;
  const int w   = tid >> 6;
  const int gw  = blockIdx.x * WPB + w;           // global wave 0..511
  const int rb  = gw * 4;                         // this wave's 4 rows
  const int cb  = l * 4;                          // column base per 256-chunk

  // ---- J rows rb..rb+3: J[j][k] <-> row rb+j, cols k*256 + 4l
  f32x4 J[4][8];
#pragma unroll
  for (int j = 0; j < 4; ++j) {
    const float mu = M_ * u[rb + j];
#pragma unroll
    for (int k = 0; k < 8; ++k) {
      const int c = k * 256 + cb;
      const f32x4 wv = *(const f32x4*)(W + (size_t)(rb + j) * NN + c);
      const f32x4 vv = *(const f32x4*)(v + c);
      J[j][k] = G_ * wv - BOFF + mu * vv;
    }
  }

  float h[4];
#pragma unroll
  for (int j = 0; j < 4; ++j) h[j] = h0[rb + j];

  const f32x4 zero4 = {0.f, 0.f, 0.f, 0.f};
  float* const buf0 = xbuf;
  float* const buf1 = xbuf + NN;
  const float* const pb0 = buf0 + cb + 1024;   // +4096B bias for imm offsets
  const float* const pb1 = buf1 + cb + 1024;

  for (int t = 0; t < TT; ++t) {
    // I_t row t: issued before the poll ("memory" clobber pins it here), so
    // its latency hides under the poll round trip.
    float icur[4];
#pragma unroll
    for (int j = 0; j < 4; ++j)
      icur[j] = I_t[(size_t)t * NN + rb + j];

    const bool enc = ((t >> 1) & 1) != 0;   // x(t) stored sign-flipped?
    f32x4 c[8];

    if (t == 0) {
      // x(0) = relu(h0), normal cached loads
#pragma unroll
      for (int k = 0; k < 8; ++k) {
        const f32x4 xv = *(const f32x4*)(h0 + k * 256 + cb);
        c[k] = __builtin_elementwise_max(xv, zero4);
      }
    } else {
      const float* pb = (t & 1) ? pb1 : pb0;
      unsigned spins = 0;
      if (enc) {
        // fresh values have sign SET: AND-tree of all 32 words must be < 0
        for (;;) {
          poll8(pb, c);
          i32x4 s = (bc(c[0]) & bc(c[1])) & (bc(c[2]) & bc(c[3]));
          s &= (bc(c[4]) & bc(c[5])) & (bc(c[6]) & bc(c[7]));
          const int m = (s.x & s.y) & (s.z & s.w);
          if (__all(m < 0)) break;
          if (++spins > (1u << 20)) break;   // escape hatch; never hit co-resident
        }
      } else {
        // fresh values have sign CLEAR: OR-tree of all 32 words must be >= 0
        for (;;) {
          poll8(pb, c);
          i32x4 s = (bc(c[0]) | bc(c[1])) | (bc(c[2]) | bc(c[3]));
          s |= (bc(c[4]) | bc(c[5])) | (bc(c[6]) | bc(c[7]));
          const int m = (s.x | s.y) | (s.z | s.w);
          if (__all(m >= 0)) break;
          if (++spins > (1u << 20)) break;
        }
      }
    }

    // ---- p = J @ x, with x = enc ? -c : c. Sign applied AFTER the reduction
    // (negation commutes exactly with FP add/mul, so numerics are unchanged).
    f32x4 p4[4] = {zero4, zero4, zero4, zero4};
#pragma unroll
    for (int k = 0; k < 8; ++k) {
#pragma unroll
      for (int j = 0; j < 4; ++j)
        p4[j] = __builtin_elementwise_fma(J[j][k], c[k], p4[j]);  // v_pk_fma_f32
    }
    float p[4];
#pragma unroll
    for (int j = 0; j < 4; ++j)
      p[j] = (p4[j].x + p4[j].y) + (p4[j].z + p4[j].w);
#pragma unroll
    for (int m = 32; m >= 1; m >>= 1) {
#pragma unroll
      for (int j = 0; j < 4; ++j) p[j] += __shfl_xor(p[j], m, 64);
    }
#pragma unroll
    for (int j = 0; j < 4; ++j) {
      const float pj = enc ? -p[j] : p[j];
      h[j] = fmaf(COEF, pj + icur[j] - h[j], h[j]);
    }

    // ---- publish x(t+1) = relu(h), sign-encoded: this IS the barrier.
    if (t + 1 < TT) {
      const bool encN = (((t + 1) >> 1) & 1) != 0;
      if (l == 0) {
        // integer sign handling: exact, and maps -0.0 from fmax ties to the
        // correct phase bit deterministically.
        int b0 = __builtin_bit_cast(int, fmaxf(h[0], 0.f));
        int b1 = __builtin_bit_cast(int, fmaxf(h[1], 0.f));
        int b2 = __builtin_bit_cast(int, fmaxf(h[2], 0.f));
        int b3 = __builtin_bit_cast(int, fmaxf(h[3], 0.f));
        if (encN) { b0 |= 0x80000000; b1 |= 0x80000000; b2 |= 0x80000000; b3 |= 0x80000000; }
        else      { b0 &= 0x7fffffff; b1 &= 0x7fffffff; b2 &= 0x7fffffff; b3 &= 0x7fffffff; }
        union { int i[2]; unsigned long long u; } a, b;
        a.i[0] = b0; a.i[1] = b1; b.i[0] = b2; b.i[1] = b3;
        float* const dst = ((t + 1) & 1) ? buf1 : buf0;
        unsigned long long* dp = (unsigned long long*)(dst + rb);
        __hip_atomic_store(dp,     a.u, __ATOMIC_RELAXED, __HIP_MEMORY_SCOPE_AGENT);
        __hip_atomic_store(dp + 1, b.u, __ATOMIC_RELAXED, __HIP_MEMORY_SCOPE_AGENT);
      }
    }
    // trace store (off the critical path, after the x publish)
    if (l == 0) {
      f32x4 hv; hv.x = h[0]; hv.y = h[1]; hv.z = h[2]; hv.w = h[3];
      __builtin_nontemporal_store(hv, (f32x4*)(out_h + (size_t)t * NN + rb));
    }
  }
}

__global__ __launch_bounds__(256)
void readout(const float* __restrict__ h_all,
             const float* __restrict__ ro_w,
             const float* __restrict__ ro_b,
             float* __restrict__ y)
{
  __shared__ float red[4];
  const int t   = blockIdx.x;
  const int tid = threadIdx.x;
  const float* h = h_all + (size_t)t * NN;
  const int base = tid * 8;

  const float4 a0 = *(const float4*)(h + base);
  const float4 a1 = *(const float4*)(h + base + 4);
  const float4 w0 = *(const float4*)(ro_w + base);
  const float4 w1 = *(const float4*)(ro_w + base + 4);

  float s = a0.x * w0.x + a0.y * w0.y + a0.z * w0.z + a0.w * w0.w
          + a1.x * w1.x + a1.y * w1.y + a1.z * w1.z + a1.w * w1.w;
#pragma unroll
  for (int m = 32; m >= 1; m >>= 1) s += __shfl_xor(s, m, 64);

  if ((tid & 63) == 0) red[tid >> 6] = s;
  __syncthreads();
  if (tid == 0) y[t] = red[0] + red[1] + red[2] + red[3] + ro_b[0];
}

extern "C" void kernel_launch(void* const* d_in, const int* in_sizes, int n_in,
                              void* d_out, int out_size, void* d_ws, size_t ws_size,
                              hipStream_t stream)
{
  const float* I_t  = (const float*)d_in[0];
  const float* h0   = (const float*)d_in[1];
  const float* W    = (const float*)d_in[2];
  const float* u    = (const float*)d_in[3];
  const float* v    = (const float*)d_in[4];
  const float* ro_w = (const float*)d_in[5];
  const float* ro_b = (const float*)d_in[6];

  float* y    = (float*)d_out;             // [TT]
  float* outh = (float*)d_out + TT;        // [TT][NN]

  float* xbuf = (float*)d_ws;              // 2*NN floats

  init_xbufs<<<NN / TPB, TPB, 0, stream>>>(xbuf);
  rnn_persist<<<NBLK, TPB, 0, stream>>>(I_t, h0, W, u, v, outh, xbuf);
  readout<<<TT, 256, 0, stream>>>(outh, ro_w, ro_b, y);
}

// Round 2
// 23661.409 us; speedup vs baseline: 1.8934x; 1.8934x over previous
//
#include <hip/hip_runtime.h>
#include <cstdint>
#include <cstddef>

// LowRankRNN: h_{t+1} = h + coef*(-h + J@relu(h) + I_t),  J = G*W - B/N + M u v^T
//
// Persistent kernel, 64 blocks x 512 threads (1 block/CU), J in registers
// (128 f32/lane). Sync: sign-bit-encoded data IS the flag. x = relu(h) >= 0,
// so x(t) is stored with its sign bit forced to phase enc(t)=(t>>1)&1 (exact;
// decode = clear sign bit). Two global buffers alternate by t&1; consecutive
// occupants of a buffer have opposite phase, so stale data never satisfies
// the poll.
//
// R2 change vs R1: de-duplicate polling. In R1 all 512 waves polled the whole
// 8KB vector coherently (4MB/round, 512 readers/line) -> LLC hot-line
// serialization, 5.4us/step. Now wave w of each block polls ONLY chunk w
// (1 dwordx4 sc0 sc1 per lane per round; 512KB/round total, 64 readers/line),
// decodes it, writes it to LDS; one __syncthreads; all waves read the full x
// from LDS (conflict-free ds_read_b128). LDS double-buffered by t&1 (WAR-safe
// with a single barrier per step: reaching the write of buffer b at t+2
// requires passing the t+1 barrier, which happens after all step-t reads of b).
//
// Overwrite safety (global): a block publishes x(t+2) only after all its waves
// acquired x(t+1); every block published x(t+1) only after passing its step-t
// barrier, i.e. after all its waves acquired x(t). So no producer can clobber
// a buffer any wave still needs. Per-32-bit-slot store atomicity is the only
// ordering requirement; partial arrival is caught per-word by the sign check.

constexpr int   NN   = 2048;
constexpr int   TT   = 8192;
constexpr float COEF = 0.001f;             // DT/TAU
constexpr float G_   = 2.0f;
constexpr float BOFF = 10.0f / 2048.0f;    // B/N
constexpr float M_   = 1.5f;

constexpr int NBLK = 64;    // 1 block/CU
constexpr int TPB  = 512;   // 8 waves
constexpr int WPB  = TPB / 64;

typedef float f32x4 __attribute__((ext_vector_type(4)));
typedef int   i32x4 __attribute__((ext_vector_type(4)));

__device__ __forceinline__ i32x4 bc(const f32x4 x) {
  return __builtin_bit_cast(i32x4, x);
}

// buf0 polled first at t=2 expecting sign-SET  -> init sign-clear (waits)
// buf1 polled first at t=1 expecting sign-CLEAR -> init sign-set  (waits)
__global__ void init_xbufs(float* xb) {
  const int i = blockIdx.x * blockDim.x + threadIdx.x;   // 0..NN-1
  __hip_atomic_store(xb + i,      0.0f,  __ATOMIC_RELAXED, __HIP_MEMORY_SCOPE_AGENT);
  __hip_atomic_store(xb + NN + i, -1.0f, __ATOMIC_RELAXED, __HIP_MEMORY_SCOPE_AGENT);
}

// One LLC-coherent 16B load + waitcnt in a single asm block (waitcnt inside
// the producing asm => consumers ordered by register dataflow; rule-#18 safe).
__device__ __forceinline__ f32x4 poll1(const float* p) {
  f32x4 c;
  asm volatile("global_load_dwordx4 %0, %1, off sc0 sc1\n\t"
               "s_waitcnt vmcnt(0)"
               : "=&v"(c) : "v"(p) : "memory");
  return c;
}

__global__ __launch_bounds__(TPB, 2)
void rnn_persist(const float* __restrict__ I_t,
                 const float* __restrict__ h0,
                 const float* __restrict__ W,
                 const float* __restrict__ u,
                 const float* __restrict__ v,
                 float* __restrict__ out_h,   // d_out + TT, [TT][NN]
                 float* __restrict__ xbuf)    // 2*NN floats
{
  __shared__ f32x4 xs[2][NN / 4];             // 16 KB, double-buffered x

  const int tid = threadIdx.x;
  const int l   = tid & 63;
  const int w   = tid >> 6;
  const int gw  = blockIdx.x * WPB + w;           // global wave 0..511
  const int rb  = gw * 4;                         // this wave's 4 rows
  const int cb  = l * 4;                          // column base per 256-chunk

  // ---- J rows rb..rb+3: J[j][k] <-> row rb+j, cols k*256 + 4l
  f32x4 J[4][8];
#pragma unroll
  for (int j = 0; j < 4; ++j) {
    const float mu = M_ * u[rb + j];
#pragma unroll
    for (int k = 0; k < 8; ++k) {
      const int c = k * 256 + cb;
      const f32x4 wv = *(const f32x4*)(W + (size_t)(rb + j) * NN + c);
      const f32x4 vv = *(const f32x4*)(v + c);
      J[j][k] = G_ * wv - BOFF + mu * vv;
    }
  }

  float h[4];
#pragma unroll
  for (int j = 0; j < 4; ++j) h[j] = h0[rb + j];

  const f32x4 zero4 = {0.f, 0.f, 0.f, 0.f};

  for (int t = 0; t < TT; ++t) {
    // I_t row t: issued before the poll so its latency hides under the RT
    float icur[4];
#pragma unroll
    for (int j = 0; j < 4; ++j)
      icur[j] = I_t[(size_t)t * NN + rb + j];

    const int bsel = t & 1;

    // ---- acquire this wave's chunk w of x(t)
    f32x4 c;
    if (t == 0) {
      const f32x4 hv = *(const f32x4*)(h0 + w * 256 + cb);
      c = __builtin_elementwise_max(hv, zero4);   // x(0) = relu(h0)
    } else {
      const bool enc = ((t >> 1) & 1) != 0;       // x(t) stored sign-flipped?
      const float* pb = xbuf + bsel * NN + w * 256 + cb;
      unsigned spins = 0;
      if (enc) {
        for (;;) {  // fresh values have sign SET: all 4 words negative
          c = poll1(pb);
          const i32x4 b = bc(c);
          if (__all(((b.x & b.y) & (b.z & b.w)) < 0)) break;
          if (++spins > (1u << 22)) break;        // escape hatch; never hit
        }
      } else {
        for (;;) {  // fresh values have sign CLEAR: all 4 words non-negative
          c = poll1(pb);
          const i32x4 b = bc(c);
          if (__all(((b.x | b.y) | (b.z | b.w)) >= 0)) break;
          if (++spins > (1u << 22)) break;
        }
      }
      i32x4 b = bc(c);
      b &= 0x7fffffff;                            // exact decode: clear sign
      c = __builtin_bit_cast(f32x4, b);
    }

    xs[bsel][w * 64 + l] = c;                     // ds_write_b128
    __syncthreads();

    // ---- p = J @ x from LDS (values already relu'd + decoded)
    f32x4 p4[4] = {zero4, zero4, zero4, zero4};
#pragma unroll
    for (int k = 0; k < 8; ++k) {
      const f32x4 xv = xs[bsel][k * 64 + l];      // ds_read_b128, conflict-free
#pragma unroll
      for (int j = 0; j < 4; ++j)
        p4[j] = __builtin_elementwise_fma(J[j][k], xv, p4[j]);  // v_pk_fma_f32
    }
    float p[4];
#pragma unroll
    for (int j = 0; j < 4; ++j)
      p[j] = (p4[j].x + p4[j].y) + (p4[j].z + p4[j].w);
#pragma unroll
    for (int m = 32; m >= 1; m >>= 1) {
#pragma unroll
      for (int j = 0; j < 4; ++j) p[j] += __shfl_xor(p[j], m, 64);
    }
#pragma unroll
    for (int j = 0; j < 4; ++j)
      h[j] = fmaf(COEF, p[j] + icur[j] - h[j], h[j]);

    // ---- publish x(t+1) = relu(h), sign-encoded: this IS the barrier.
    if (t + 1 < TT) {
      const bool encN = (((t + 1) >> 1) & 1) != 0;
      if (l == 0) {
        int b0 = __builtin_bit_cast(int, fmaxf(h[0], 0.f));
        int b1 = __builtin_bit_cast(int, fmaxf(h[1], 0.f));
        int b2 = __builtin_bit_cast(int, fmaxf(h[2], 0.f));
        int b3 = __builtin_bit_cast(int, fmaxf(h[3], 0.f));
        if (encN) { b0 |= 0x80000000; b1 |= 0x80000000; b2 |= 0x80000000; b3 |= 0x80000000; }
        else      { b0 &= 0x7fffffff; b1 &= 0x7fffffff; b2 &= 0x7fffffff; b3 &= 0x7fffffff; }
        union { int i[2]; unsigned long long u; } a, b;
        a.i[0] = b0; a.i[1] = b1; b.i[0] = b2; b.i[1] = b3;
        float* const dst = xbuf + ((t + 1) & 1) * NN;
        unsigned long long* dp = (unsigned long long*)(dst + rb);
        __hip_atomic_store(dp,     a.u, __ATOMIC_RELAXED, __HIP_MEMORY_SCOPE_AGENT);
        __hip_atomic_store(dp + 1, b.u, __ATOMIC_RELAXED, __HIP_MEMORY_SCOPE_AGENT);
      }
    }
    // trace store (off the critical path, after the x publish)
    if (l == 0) {
      f32x4 hv; hv.x = h[0]; hv.y = h[1]; hv.z = h[2]; hv.w = h[3];
      __builtin_nontemporal_store(hv, (f32x4*)(out_h + (size_t)t * NN + rb));
    }
  }
}

__global__ __launch_bounds__(256)
void readout(const float* __restrict__ h_all,
             const float* __restrict__ ro_w,
             const float* __restrict__ ro_b,
             float* __restrict__ y)
{
  __shared__ float red[4];
  const int t   = blockIdx.x;
  const int tid = threadIdx.x;
  const float* h = h_all + (size_t)t * NN;
  const int base = tid * 8;

  const float4 a0 = *(const float4*)(h + base);
  const float4 a1 = *(const float4*)(h + base + 4);
  const float4 w0 = *(const float4*)(ro_w + base);
  const float4 w1 = *(const float4*)(ro_w + base + 4);

  float s = a0.x * w0.x + a0.y * w0.y + a0.z * w0.z + a0.w * w0.w
          + a1.x * w1.x + a1.y * w1.y + a1.z * w1.z + a1.w * w1.w;
#pragma unroll
  for (int m = 32; m >= 1; m >>= 1) s += __shfl_xor(s, m, 64);

  if ((tid & 63) == 0) red[tid >> 6] = s;
  __syncthreads();
  if (tid == 0) y[t] = red[0] + red[1] + red[2] + red[3] + ro_b[0];
}

extern "C" void kernel_launch(void* const* d_in, const int* in_sizes, int n_in,
                              void* d_out, int out_size, void* d_ws, size_t ws_size,
                              hipStream_t stream)
{
  const float* I_t  = (const float*)d_in[0];
  const float* h0   = (const float*)d_in[1];
  const float* W    = (const float*)d_in[2];
  const float* u    = (const float*)d_in[3];
  const float* v    = (const float*)d_in[4];
  const float* ro_w = (const float*)d_in[5];
  const float* ro_b = (const float*)d_in[6];

  float* y    = (float*)d_out;             // [TT]
  float* outh = (float*)d_out + TT;        // [TT][NN]

  float* xbuf = (float*)d_ws;              // 2*NN floats

  init_xbufs<<<NN / TPB, TPB, 0, stream>>>(xbuf);
  rnn_persist<<<NBLK, TPB, 0, stream>>>(I_t, h0, W, u, v, outh, xbuf);
  readout<<<TT, 256, 0, stream>>>(outh, ro_w, ro_b, y);
}

// Round 4
// 16739.651 us; speedup vs baseline: 2.6763x; 1.4135x over previous
//
#include <hip/hip_runtime.h>
#include <cstdint>
#include <cstddef>

// LowRankRNN: h_{t+1} = h + coef*(-h + J@relu(h) + I_t),  J = G*W - B/N + M u v^T
//
// Persistent kernel, 64 blocks x 512 threads (1 block/CU), J in registers.
// Sync: sign-bit-encoded data IS the flag (x = relu(h) >= 0; x(t) stored with
// sign bit forced to phase enc(t)=(t>>1)&1; decode = clear sign bit; two
// global buffers alternate by t&1 so stale data never satisfies the poll).
// Wave w of each block polls only chunk w (1 dwordx4 sc0 sc1 per lane),
// decodes into LDS; one __syncthreads; all waves read x from LDS.
//
// R4 = R3 with the compile fix: DPP/swizzle control words must be integral
// constant expressions -> template<int> helpers instead of runtime args.
//
// R3 changes (all bit-identical numerics vs R2):
//  1. I_t software-pipelined 2 steps ahead (two parity-selected f32x4 regs):
//     in R2 the I_t row was issued ~0 cy before the poll, so every poll
//     round's vmcnt(0) ate a ~1000 cy HBM miss. Now the load is issued a full
//     step early and is long done when the poll drains.
//  2. Trace store: nontemporal -> plain cached store (acks from L2 instead of
//     an HBM write-ack inside the next poll's vmcnt(0) drain).
//  3. Reduce: same butterfly pairing order (32,16,8,4,2,1 — bit-identical),
//     but xor8/2/1 via single-VALU DPP (row_ror:8, quad_perm), xor16/4 via
//     ds_swizzle, xor32 via __shfl_xor. ~350 -> ~180 cy on the publish path.
//  4. Publish: one global_store_dwordx4 sc0 sc1 (write-through; the protocol
//     only needs per-dword atomicity) instead of two 8B atomic stores.
//
// Overwrite safety unchanged: a block publishes x(t+2) only after all its
// waves acquired x(t+1), which required every block to have published x(t+1),
// which required their step-t barrier, i.e. all step-t reads of buffer t&1
// are done before anyone can write it again.

constexpr int   NN   = 2048;
constexpr int   TT   = 8192;
constexpr float COEF = 0.001f;             // DT/TAU
constexpr float G_   = 2.0f;
constexpr float BOFF = 10.0f / 2048.0f;    // B/N
constexpr float M_   = 1.5f;

constexpr int NBLK = 64;    // 1 block/CU
constexpr int TPB  = 512;   // 8 waves
constexpr int WPB  = TPB / 64;

typedef float f32x4 __attribute__((ext_vector_type(4)));
typedef int   i32x4 __attribute__((ext_vector_type(4)));

__device__ __forceinline__ i32x4 bc(const f32x4 x) {
  return __builtin_bit_cast(i32x4, x);
}

// buf0 polled first at t=2 expecting sign-SET  -> init sign-clear (waits)
// buf1 polled first at t=1 expecting sign-CLEAR -> init sign-set  (waits)
__global__ void init_xbufs(float* xb) {
  const int i = blockIdx.x * blockDim.x + threadIdx.x;   // 0..NN-1
  __hip_atomic_store(xb + i,      0.0f,  __ATOMIC_RELAXED, __HIP_MEMORY_SCOPE_AGENT);
  __hip_atomic_store(xb + NN + i, -1.0f, __ATOMIC_RELAXED, __HIP_MEMORY_SCOPE_AGENT);
}

// One LLC-coherent 16B load + waitcnt in a single asm block (waitcnt inside
// the producing asm => consumers ordered by register dataflow; rule-#18 safe).
__device__ __forceinline__ f32x4 poll1(const float* p) {
  f32x4 c;
  asm volatile("global_load_dwordx4 %0, %1, off sc0 sc1\n\t"
               "s_waitcnt vmcnt(0)"
               : "=&v"(c) : "v"(p) : "memory");
  return c;
}

// write-through 16B publish store (visible at LLC; per-dword atomicity)
__device__ __forceinline__ void store_wt(float* p, f32x4 v) {
  asm volatile("global_store_dwordx4 %0, %1, off sc0 sc1"
               :: "v"(p), "v"(v) : "memory");
}

// butterfly helpers — value-identical to p += __shfl_xor(p, m).
// Control words must be integral constant expressions -> template params.
template <int CTRL>
__device__ __forceinline__ float xadd_dpp(float v) {
  const int t = __builtin_amdgcn_update_dpp(0, __builtin_bit_cast(int, v),
                                            CTRL, 0xF, 0xF, false);
  return v + __builtin_bit_cast(float, t);
}
template <int PAT>
__device__ __forceinline__ float xadd_swz(float v) {
  const int t = __builtin_amdgcn_ds_swizzle(__builtin_bit_cast(int, v), PAT);
  return v + __builtin_bit_cast(float, t);
}

__global__ __launch_bounds__(TPB, 2)
void rnn_persist(const float* __restrict__ I_t,
                 const float* __restrict__ h0,
                 const float* __restrict__ W,
                 const float* __restrict__ u,
                 const float* __restrict__ v,
                 float* __restrict__ out_h,   // d_out + TT, [TT][NN]
                 float* __restrict__ xbuf)    // 2*NN floats
{
  __shared__ f32x4 xs[2][NN / 4];             // 16 KB, double-buffered x

  const int tid = threadIdx.x;
  const int l   = tid & 63;
  const int w   = tid >> 6;
  const int gw  = blockIdx.x * WPB + w;           // global wave 0..511
  const int rb  = gw * 4;                         // this wave's 4 rows
  const int cb  = l * 4;                          // column base per 256-chunk

  // ---- J rows rb..rb+3: J[j][k] <-> row rb+j, cols k*256 + 4l
  f32x4 J[4][8];
#pragma unroll
  for (int j = 0; j < 4; ++j) {
    const float mu = M_ * u[rb + j];
#pragma unroll
    for (int k = 0; k < 8; ++k) {
      const int c = k * 256 + cb;
      const f32x4 wv = *(const f32x4*)(W + (size_t)(rb + j) * NN + c);
      const f32x4 vv = *(const f32x4*)(v + c);
      J[j][k] = G_ * wv - BOFF + mu * vv;
    }
  }

  float h[4];
#pragma unroll
  for (int j = 0; j < 4; ++j) h[j] = h0[rb + j];

  const f32x4 zero4 = {0.f, 0.f, 0.f, 0.f};

  // ---- I_t pipeline: iva holds even-t rows, ivb odd-t rows, issued >=1 step
  // ahead so the poll's vmcnt(0) never waits on an I_t HBM miss.
  f32x4 iva = *(const f32x4*)(I_t + rb);              // row 0
  f32x4 ivb = *(const f32x4*)(I_t + (size_t)NN + rb); // row 1 (in flight)

  for (int t = 0; t < TT; ++t) {
    const f32x4 icur4 = (t & 1) ? ivb : iva;
    const int bsel = t & 1;

    // ---- acquire this wave's chunk w of x(t)
    f32x4 c;
    if (t == 0) {
      const f32x4 hv = *(const f32x4*)(h0 + w * 256 + cb);
      c = __builtin_elementwise_max(hv, zero4);   // x(0) = relu(h0)
    } else {
      const bool enc = ((t >> 1) & 1) != 0;       // x(t) stored sign-flipped?
      const float* pb = xbuf + bsel * NN + w * 256 + cb;
      unsigned spins = 0;
      if (enc) {
        for (;;) {  // fresh values have sign SET: all 4 words negative
          c = poll1(pb);
          const i32x4 b = bc(c);
          if (__all(((b.x & b.y) & (b.z & b.w)) < 0)) break;
          if (++spins > (1u << 22)) break;        // escape hatch; never hit
        }
      } else {
        for (;;) {  // fresh values have sign CLEAR: all 4 words non-negative
          c = poll1(pb);
          const i32x4 b = bc(c);
          if (__all(((b.x | b.y) | (b.z | b.w)) >= 0)) break;
          if (++spins > (1u << 22)) break;
        }
      }
      i32x4 b = bc(c);
      b &= 0x7fffffff;                            // exact decode: clear sign
      c = __builtin_bit_cast(f32x4, b);
    }

    // ---- issue I_t row t+2 now (full step of slack; same parity slot as t)
    if (t + 2 < TT) {
      const f32x4 nv = *(const f32x4*)(I_t + (size_t)(t + 2) * NN + rb);
      if (t & 1) ivb = nv; else iva = nv;
    }

    xs[bsel][w * 64 + l] = c;                     // ds_write_b128
    __syncthreads();

    // ---- p = J @ x from LDS (values already relu'd + decoded)
    f32x4 p4[4] = {zero4, zero4, zero4, zero4};
#pragma unroll
    for (int k = 0; k < 8; ++k) {
      const f32x4 xv = xs[bsel][k * 64 + l];      // ds_read_b128, conflict-free
#pragma unroll
      for (int j = 0; j < 4; ++j)
        p4[j] = __builtin_elementwise_fma(J[j][k], xv, p4[j]);  // v_pk_fma_f32
    }
    float p[4];
#pragma unroll
    for (int j = 0; j < 4; ++j)
      p[j] = (p4[j].x + p4[j].y) + (p4[j].z + p4[j].w);

    // ---- wave allreduce, same pairing order as p += __shfl_xor(p, m) for
    // m = 32,16,8,4,2,1 (bit-identical), with DPP/swizzle for low latency.
#pragma unroll
    for (int j = 0; j < 4; ++j) {
      p[j] += __shfl_xor(p[j], 32, 64);     // xor32 (ds_permute/permlane)
      p[j] = xadd_swz<0x401F>(p[j]);        // xor16 (ds_swizzle)
      p[j] = xadd_dpp<0x128>(p[j]);         // xor8  (DPP row_ror:8)
      p[j] = xadd_swz<0x101F>(p[j]);        // xor4  (ds_swizzle)
      p[j] = xadd_dpp<0x4E>(p[j]);          // xor2  (DPP quad_perm [2,3,0,1])
      p[j] = xadd_dpp<0xB1>(p[j]);          // xor1  (DPP quad_perm [1,0,3,2])
    }

    const float ic[4] = {icur4.x, icur4.y, icur4.z, icur4.w};
#pragma unroll
    for (int j = 0; j < 4; ++j)
      h[j] = fmaf(COEF, p[j] + ic[j] - h[j], h[j]);

    // ---- publish x(t+1) = relu(h), sign-encoded: this IS the barrier.
    if (t + 1 < TT) {
      const bool encN = (((t + 1) >> 1) & 1) != 0;
      if (l == 0) {
        i32x4 e;
        e.x = __builtin_bit_cast(int, fmaxf(h[0], 0.f));
        e.y = __builtin_bit_cast(int, fmaxf(h[1], 0.f));
        e.z = __builtin_bit_cast(int, fmaxf(h[2], 0.f));
        e.w = __builtin_bit_cast(int, fmaxf(h[3], 0.f));
        if (encN) e |= 0x80000000; else e &= 0x7fffffff;
        store_wt(xbuf + ((t + 1) & 1) * NN + rb, __builtin_bit_cast(f32x4, e));
      }
    }
    // trace store: plain cached store (fast L2 ack; off the critical path)
    if (l == 0) {
      f32x4 hv; hv.x = h[0]; hv.y = h[1]; hv.z = h[2]; hv.w = h[3];
      *(f32x4*)(out_h + (size_t)t * NN + rb) = hv;
    }
  }
}

__global__ __launch_bounds__(256)
void readout(const float* __restrict__ h_all,
             const float* __restrict__ ro_w,
             const float* __restrict__ ro_b,
             float* __restrict__ y)
{
  __shared__ float red[4];
  const int t   = blockIdx.x;
  const int tid = threadIdx.x;
  const float* h = h_all + (size_t)t * NN;
  const int base = tid * 8;

  const float4 a0 = *(const float4*)(h + base);
  const float4 a1 = *(const float4*)(h + base + 4);
  const float4 w0 = *(const float4*)(ro_w + base);
  const float4 w1 = *(const float4*)(ro_w + base + 4);

  float s = a0.x * w0.x + a0.y * w0.y + a0.z * w0.z + a0.w * w0.w
          + a1.x * w1.x + a1.y * w1.y + a1.z * w1.z + a1.w * w1.w;
#pragma unroll
  for (int m = 32; m >= 1; m >>= 1) s += __shfl_xor(s, m, 64);

  if ((tid & 63) == 0) red[tid >> 6] = s;
  __syncthreads();
  if (tid == 0) y[t] = red[0] + red[1] + red[2] + red[3] + ro_b[0];
}

extern "C" void kernel_launch(void* const* d_in, const int* in_sizes, int n_in,
                              void* d_out, int out_size, void* d_ws, size_t ws_size,
                              hipStream_t stream)
{
  const float* I_t  = (const float*)d_in[0];
  const float* h0   = (const float*)d_in[1];
  const float* W    = (const float*)d_in[2];
  const float* u    = (const float*)d_in[3];
  const float* v    = (const float*)d_in[4];
  const float* ro_w = (const float*)d_in[5];
  const float* ro_b = (const float*)d_in[6];

  float* y    = (float*)d_out;             // [TT]
  float* outh = (float*)d_out + TT;        // [TT][NN]

  float* xbuf = (float*)d_ws;              // 2*NN floats

  init_xbufs<<<NN / TPB, TPB, 0, stream>>>(xbuf);
  rnn_persist<<<NBLK, TPB, 0, stream>>>(I_t, h0, W, u, v, outh, xbuf);
  readout<<<TT, 256, 0, stream>>>(outh, ro_w, ro_b, y);
}